// Round 12
// baseline (7617.942 us; speedup 1.0000x reference)
//
#include <hip/hip_runtime.h>
#include <hip/hip_bf16.h>

typedef _Float16 f16x8 __attribute__((ext_vector_type(8)));
typedef float    f32x4 __attribute__((ext_vector_type(4)));
typedef float    f32x2 __attribute__((ext_vector_type(2)));

#define T_STEPS 1024
#define BATCH   128
#define DH      256
#define BH      (BATCH * DH)
#define REC_BLOCKS 128

#define BM 128
#define BN 128
#define BK 64

// ---------------------------------------------------------------------------
// GEMM staging (unchanged from R9; caller guarantees t < 256)
// ---------------------------------------------------------------------------
__device__ __forceinline__ void stage_tile(const float* __restrict__ src,
                                           int row0, int kc,
                                           unsigned short* hi, unsigned short* lo,
                                           int t) {
#pragma unroll
  for (int i = 0; i < 8; ++i) {
    int f   = i * 256 + t;
    int row = f >> 4;
    int q   = f & 15;
    const float4 v = *(const float4*)&src[(size_t)(row0 + row) * 256 + kc + q * 4];
    _Float16 h0 = (_Float16)v.x, h1 = (_Float16)v.y,
             h2 = (_Float16)v.z, h3 = (_Float16)v.w;
    _Float16 l0 = (_Float16)(v.x - (float)h0), l1 = (_Float16)(v.y - (float)h1),
             l2 = (_Float16)(v.z - (float)h2), l3 = (_Float16)(v.w - (float)h3);
    unsigned int off = (unsigned int)(row * 128 + q * 8) ^ ((row & 7) << 4);
    union { _Float16 h[4]; uint2 u; } ph, pl;
    ph.h[0] = h0; ph.h[1] = h1; ph.h[2] = h2; ph.h[3] = h3;
    pl.h[0] = l0; pl.h[1] = l1; pl.h[2] = l2; pl.h[3] = l3;
    *(uint2*)((char*)hi + off) = ph.u;
    *(uint2*)((char*)lo + off) = pl.u;
  }
}

__device__ __forceinline__ float tanh_fast(float x) {
  float xc = fminf(9.0f, fmaxf(-9.0f, x));
  float e2 = __builtin_amdgcn_exp2f(2.885390082f * xc);
  return 1.0f - 2.0f * __builtin_amdgcn_rcpf(e2 + 1.0f);
}

__device__ __forceinline__ float dpp_ror_sum16(float x) {
  float y;
  asm("v_add_f32_dpp %0, %1, %1 row_ror:8 row_mask:0xf bank_mask:0xf"
      : "=v"(y) : "v"(x));
  asm("v_add_f32_dpp %0, %1, %1 row_ror:4 row_mask:0xf bank_mask:0xf"
      : "=v"(x) : "v"(y));
  asm("v_add_f32_dpp %0, %1, %1 row_ror:2 row_mask:0xf bank_mask:0xf"
      : "=v"(y) : "v"(x));
  asm("v_add_f32_dpp %0, %1, %1 row_ror:1 row_mask:0xf bank_mask:0xf"
      : "=v"(x) : "v"(y));
  return x;
}

#define LDS_BARRIER() \
  asm volatile("s_waitcnt lgkmcnt(0)\n\ts_barrier" ::: "memory")

// ---------------------------------------------------------------------------
// FUSED kernel. Blocks [0,128): recurrence (R9 code + xp-ready polling).
// Blocks [128, 128+2048): GEMM tiles; gid=bid-128, t=gid>>1, n0=(gid&1)*128.
// Each GEMM block release-increments done[t] after its epilogue; xp[t] is
// ready when done[t]==2. Rec polls with acquire loads only while tknown<=s+2
// (first ~30 steps); afterwards it's a 2-op register check. waves_per_eu(2,2)
// => 1 WG/CU => rec owns 128 CUs undisturbed, GEMM streams on the rest
// (~200us, fully hidden: GEMM produces t ~4x faster than rec consumes).
// No deadlock: rec uses 1024 of 8192 wave slots; GEMM never waits on rec.
// ---------------------------------------------------------------------------
__attribute__((amdgpu_waves_per_eu(2, 2)))
__global__ __launch_bounds__(512) void rnn_fused(
    const float* __restrict__ x,   const float* __restrict__ Wih,
    const float* __restrict__ Whh, const float* __restrict__ bih,
    const float* __restrict__ bhh, float* __restrict__ xh,
    int* __restrict__ done) {
  // LDS: GEMM needs 64KB; rec needs 2KB. 1 WG/CU so the union fits easily.
  __shared__ __align__(16) unsigned short Ah[BM * BK], Al[BM * BK];
  __shared__ __align__(16) unsigned short Bh[BN * BK], Bl[BN * BK];

  const int bid = blockIdx.x;
  const int tid = threadIdx.x;

  if (bid >= REC_BLOCKS) {
    // ---------------- GEMM role ----------------
    const int gid  = bid - REC_BLOCKS;
    const int m0   = (gid >> 1) * BM;      // = t * 128 (tile row == timestep)
    const int n0   = (gid & 1) * BN;
    const int t    = tid;                  // only t<256 active for compute
    const int lane = t & 63;
    const int wave = t >> 6;
    const int wm = wave >> 1, wn = wave & 1;

    f32x4 acc[4][4];
#pragma unroll
    for (int i = 0; i < 4; ++i)
#pragma unroll
      for (int j = 0; j < 4; ++j) acc[i][j] = (f32x4)0.0f;

    for (int kc = 0; kc < 256; kc += BK) {
      if (t < 256) {
        stage_tile(x,   m0, kc, Ah, Al, t);
        stage_tile(Wih, n0, kc, Bh, Bl, t);
      }
      __syncthreads();
      if (t < 256) {
#pragma unroll
        for (int ks = 0; ks < 2; ++ks) {
          f16x8 ah[4], al[4], bh[4], bl[4];
#pragma unroll
          for (int mi = 0; mi < 4; ++mi) {
            int row = wm * 64 + mi * 16 + (lane & 15);
            unsigned int off =
                (unsigned int)(row * 128 + ks * 64 + ((lane >> 4) << 4)) ^ ((row & 7) << 4);
            ah[mi] = *(const f16x8*)((const char*)Ah + off);
            al[mi] = *(const f16x8*)((const char*)Al + off);
          }
#pragma unroll
          for (int ni = 0; ni < 4; ++ni) {
            int row = wn * 64 + ni * 16 + (lane & 15);
            unsigned int off =
                (unsigned int)(row * 128 + ks * 64 + ((lane >> 4) << 4)) ^ ((row & 7) << 4);
            bh[ni] = *(const f16x8*)((const char*)Bh + off);
            bl[ni] = *(const f16x8*)((const char*)Bl + off);
          }
#pragma unroll
          for (int mi = 0; mi < 4; ++mi)
#pragma unroll
            for (int ni = 0; ni < 4; ++ni) {
              acc[mi][ni] = __builtin_amdgcn_mfma_f32_16x16x32_f16(ah[mi], bh[ni], acc[mi][ni], 0, 0, 0);
              acc[mi][ni] = __builtin_amdgcn_mfma_f32_16x16x32_f16(ah[mi], bl[ni], acc[mi][ni], 0, 0, 0);
              acc[mi][ni] = __builtin_amdgcn_mfma_f32_16x16x32_f16(al[mi], bh[ni], acc[mi][ni], 0, 0, 0);
            }
        }
      }
      __syncthreads();
    }
    if (t < 256) {
#pragma unroll
      for (int ni = 0; ni < 4; ++ni) {
        int col = n0 + wn * 64 + ni * 16 + (lane & 15);
        float bias = bih[col] + bhh[col];
#pragma unroll
        for (int mi = 0; mi < 4; ++mi) {
          int rbase = m0 + wm * 64 + mi * 16 + ((lane >> 4) << 2);
#pragma unroll
          for (int r = 0; r < 4; ++r)
            xh[(size_t)(rbase + r) * DH + col] = acc[mi][ni][r] + bias;
        }
      }
    }
    __syncthreads();   // drains vmcnt: all tile stores complete
    if (tid == 0)
      __hip_atomic_fetch_add(&done[m0 / BM], 1, __ATOMIC_RELEASE,
                             __HIP_MEMORY_SCOPE_AGENT);
    return;
  }

  // ---------------- Recurrence role (R9 body + polling) ----------------
  const int b    = bid;
  const int lane = tid & 63;
  const int wv   = tid >> 6;      // 0..7
  const int r    = lane >> 4;     // 0..3
  const int c    = lane & 15;     // 0..15
  const int jb   = wv * 32 + r * 8;

  float (*hs)[DH] = (float (*)[DH])Ah;   // reuse 2KB of the GEMM LDS

  f32x2 w2[8][8];
#pragma unroll
  for (int j = 0; j < 8; ++j)
#pragma unroll
    for (int q = 0; q < 4; ++q) {
      float4 v = *(const float4*)&Whh[(size_t)(jb + j) * DH + 64 * q + 4 * c];
      f32x2 lo; lo[0] = v.x; lo[1] = v.y;
      f32x2 hi; hi[0] = v.z; hi[1] = v.w;
      w2[j][2 * q]     = lo;
      w2[j][2 * q + 1] = hi;
    }

  const bool writer = (c < 8);
  const int  j      = jb + (c & 7);
  float* pcol = xh + (size_t)b * DH + j;
  const char* hb0 = (const char*)&hs[0][0] + 16 * c;
  const char* hb1 = (const char*)&hs[1][0] + 16 * c;

  int tknown = 0;   // uniform across block; monotone scan of done[]
#define WAITXP(S2)                                                             \
  while (tknown <= (S2)) {                                                     \
    if (__hip_atomic_load(&done[tknown], __ATOMIC_ACQUIRE,                     \
                          __HIP_MEMORY_SCOPE_AGENT) == 2) ++tknown;            \
  }

  if (tid < DH) hs[0][tid] = 0.0f;
  WAITXP(1)
  float xpc = 0.0f, xp1 = 0.0f;
  if (writer) { xpc = pcol[0]; xp1 = pcol[BH]; }   // steps 0,1
  __syncthreads();

#define STEP(S, P)                                                             \
  {                                                                            \
    float xp2 = 0.0f;                                                          \
    if ((S) + 2 < T_STEPS) {                                                   \
      WAITXP((S) + 2)                                                          \
      if (writer) xp2 = pcol[((size_t)(S) + 2) * BH];                          \
    }                                                                          \
    const char* hb = (P) ? hb1 : hb0;                                          \
    float4 hq0 = *(const float4*)(hb);                                         \
    float4 hq1 = *(const float4*)(hb + 256);                                   \
    float4 hq2 = *(const float4*)(hb + 512);                                   \
    float4 hq3 = *(const float4*)(hb + 768);                                   \
    f32x2 hp[8];                                                               \
    hp[0][0] = hq0.x; hp[0][1] = hq0.y;  hp[1][0] = hq0.z; hp[1][1] = hq0.w;   \
    hp[2][0] = hq1.x; hp[2][1] = hq1.y;  hp[3][0] = hq1.z; hp[3][1] = hq1.w;   \
    hp[4][0] = hq2.x; hp[4][1] = hq2.y;  hp[5][0] = hq2.z; hp[5][1] = hq2.w;   \
    hp[6][0] = hq3.x; hp[6][1] = hq3.y;  hp[7][0] = hq3.z; hp[7][1] = hq3.w;   \
    f32x2 acc[8];                                                              \
    _Pragma("unroll")                                                          \
    for (int jj = 0; jj < 8; ++jj) acc[jj] = w2[jj][0] * hp[0];                \
    _Pragma("unroll")                                                          \
    for (int kp = 1; kp < 8; ++kp)                                             \
      _Pragma("unroll")                                                        \
      for (int jj = 0; jj < 8; ++jj)                                           \
        acc[jj] = __builtin_elementwise_fma(w2[jj][kp], hp[kp], acc[jj]);      \
    float a[8];                                                                \
    _Pragma("unroll")                                                          \
    for (int jj = 0; jj < 8; ++jj) a[jj] = acc[jj][0] + acc[jj][1];            \
    _Pragma("unroll")                                                          \
    for (int jj = 0; jj < 8; ++jj) a[jj] = dpp_ror_sum16(a[jj]);               \
    const int cc = c & 7;                                                      \
    float v0 = (cc & 1) ? a[1] : a[0];                                         \
    float v1 = (cc & 1) ? a[3] : a[2];                                         \
    float v2 = (cc & 1) ? a[5] : a[4];                                         \
    float v3 = (cc & 1) ? a[7] : a[6];                                         \
    float u0 = (cc & 2) ? v1 : v0;                                             \
    float u1 = (cc & 2) ? v3 : v2;                                             \
    float sum = (cc & 4) ? u1 : u0;                                            \
    float h = tanh_fast(sum + xpc);                                            \
    if (writer) {                                                              \
      hs[(P) ^ 1][j] = h;                                                      \
      pcol[(size_t)(S) * BH] = h;                                              \
    }                                                                          \
    xpc = xp1; xp1 = xp2;                                                      \
    LDS_BARRIER();                                                             \
  }

  for (int s = 0; s < T_STEPS; s += 2) {
    STEP(s, 0)
    STEP(s + 1, 1)
  }
#undef STEP
#undef WAITXP
}

extern "C" void kernel_launch(void* const* d_in, const int* in_sizes, int n_in,
                              void* d_out, int out_size, void* d_ws, size_t ws_size,
                              hipStream_t stream) {
  const float* x   = (const float*)d_in[0];
  const float* Wih = (const float*)d_in[1];
  const float* Whh = (const float*)d_in[2];
  const float* bih = (const float*)d_in[3];
  const float* bhh = (const float*)d_in[4];
  float* out = (float*)d_out;
  int*   done = (int*)d_ws;

  hipMemsetAsync(done, 0, T_STEPS * sizeof(int), stream);
  rnn_fused<<<REC_BLOCKS + 2 * T_STEPS, dim3(512), 0, stream>>>(
      x, Wih, Whh, bih, bhh, out, done);
}

// Round 13
// 761.976 us; speedup vs baseline: 9.9976x; 9.9976x over previous
//
#include <hip/hip_runtime.h>
#include <hip/hip_bf16.h>

typedef _Float16 f16x8 __attribute__((ext_vector_type(8)));
typedef float    f32x4 __attribute__((ext_vector_type(4)));
typedef float    f32x2 __attribute__((ext_vector_type(2)));

#define T_STEPS 1024
#define BATCH   128
#define DH      256
#define BH      (BATCH * DH)
#define REC_BLOCKS 128

#define BM 128
#define BN 128
#define BK 64

// ---------------------------------------------------------------------------
// GEMM staging (unchanged; caller guarantees t < 256)
// ---------------------------------------------------------------------------
__device__ __forceinline__ void stage_tile(const float* __restrict__ src,
                                           int row0, int kc,
                                           unsigned short* hi, unsigned short* lo,
                                           int t) {
#pragma unroll
  for (int i = 0; i < 8; ++i) {
    int f   = i * 256 + t;
    int row = f >> 4;
    int q   = f & 15;
    const float4 v = *(const float4*)&src[(size_t)(row0 + row) * 256 + kc + q * 4];
    _Float16 h0 = (_Float16)v.x, h1 = (_Float16)v.y,
             h2 = (_Float16)v.z, h3 = (_Float16)v.w;
    _Float16 l0 = (_Float16)(v.x - (float)h0), l1 = (_Float16)(v.y - (float)h1),
             l2 = (_Float16)(v.z - (float)h2), l3 = (_Float16)(v.w - (float)h3);
    unsigned int off = (unsigned int)(row * 128 + q * 8) ^ ((row & 7) << 4);
    union { _Float16 h[4]; uint2 u; } ph, pl;
    ph.h[0] = h0; ph.h[1] = h1; ph.h[2] = h2; ph.h[3] = h3;
    pl.h[0] = l0; pl.h[1] = l1; pl.h[2] = l2; pl.h[3] = l3;
    *(uint2*)((char*)hi + off) = ph.u;
    *(uint2*)((char*)lo + off) = pl.u;
  }
}

__device__ __forceinline__ float tanh_fast(float x) {
  float xc = fminf(9.0f, fmaxf(-9.0f, x));
  float e2 = __builtin_amdgcn_exp2f(2.885390082f * xc);
  return 1.0f - 2.0f * __builtin_amdgcn_rcpf(e2 + 1.0f);
}

__device__ __forceinline__ float dpp_ror_sum16(float x) {
  float y;
  asm("v_add_f32_dpp %0, %1, %1 row_ror:8 row_mask:0xf bank_mask:0xf"
      : "=v"(y) : "v"(x));
  asm("v_add_f32_dpp %0, %1, %1 row_ror:4 row_mask:0xf bank_mask:0xf"
      : "=v"(x) : "v"(y));
  asm("v_add_f32_dpp %0, %1, %1 row_ror:2 row_mask:0xf bank_mask:0xf"
      : "=v"(y) : "v"(x));
  asm("v_add_f32_dpp %0, %1, %1 row_ror:1 row_mask:0xf bank_mask:0xf"
      : "=v"(x) : "v"(y));
  return x;
}

#define LDS_BARRIER() \
  asm volatile("s_waitcnt lgkmcnt(0)\n\ts_barrier" ::: "memory")

// ---------------------------------------------------------------------------
// FUSED kernel, fence-free cross-XCD protocol (R12 post-mortem: agent-scope
// acquire/release = L2 invalidate/writeback per call = 10x disaster).
// Protocol: xp data + done flags BOTH travel via RELAXED agent-scope atomics
// (sc1: bypass L2, land/serve at the MALL coherence point; no cache-
// maintenance instructions emitted). GEMM: epilogue atomic stores ->
// __syncthreads (per-thread vmcnt drain + barrier => all stores complete) ->
// tid0 relaxed fetch_add(done[t]). Rec: relaxed poll of done[], relaxed
// atomic xp loads (MALL latency ~400-700cy hidden by 2-deep prefetch).
// h stores stay normal/cached (block-private until kernel-end flush).
// Blocks [0,128) = rec (R9 body); [128,2176) = GEMM tiles, streamed on the
// remaining CUs (~250us, fully hidden under rec's ~650us).
// ---------------------------------------------------------------------------
__attribute__((amdgpu_waves_per_eu(2, 2)))
__global__ __launch_bounds__(512) void rnn_fused(
    const float* __restrict__ x,   const float* __restrict__ Wih,
    const float* __restrict__ Whh, const float* __restrict__ bih,
    const float* __restrict__ bhh, float* __restrict__ xh,
    int* __restrict__ done) {
  __shared__ __align__(16) unsigned short Ah[BM * BK], Al[BM * BK];
  __shared__ __align__(16) unsigned short Bh[BN * BK], Bl[BN * BK];

  const int bid = blockIdx.x;
  const int tid = threadIdx.x;

  if (bid >= REC_BLOCKS) {
    // ---------------- GEMM role ----------------
    const int gid  = bid - REC_BLOCKS;
    const int m0   = (gid >> 1) * BM;      // tile row == timestep*128
    const int n0   = (gid & 1) * BN;
    const int t    = tid;
    const int lane = t & 63;
    const int wave = t >> 6;
    const int wm = wave >> 1, wn = wave & 1;

    f32x4 acc[4][4];
#pragma unroll
    for (int i = 0; i < 4; ++i)
#pragma unroll
      for (int j = 0; j < 4; ++j) acc[i][j] = (f32x4)0.0f;

    for (int kc = 0; kc < 256; kc += BK) {
      if (t < 256) {
        stage_tile(x,   m0, kc, Ah, Al, t);
        stage_tile(Wih, n0, kc, Bh, Bl, t);
      }
      __syncthreads();
      if (t < 256) {
#pragma unroll
        for (int ks = 0; ks < 2; ++ks) {
          f16x8 ah[4], al[4], bh[4], bl[4];
#pragma unroll
          for (int mi = 0; mi < 4; ++mi) {
            int row = wm * 64 + mi * 16 + (lane & 15);
            unsigned int off =
                (unsigned int)(row * 128 + ks * 64 + ((lane >> 4) << 4)) ^ ((row & 7) << 4);
            ah[mi] = *(const f16x8*)((const char*)Ah + off);
            al[mi] = *(const f16x8*)((const char*)Al + off);
          }
#pragma unroll
          for (int ni = 0; ni < 4; ++ni) {
            int row = wn * 64 + ni * 16 + (lane & 15);
            unsigned int off =
                (unsigned int)(row * 128 + ks * 64 + ((lane >> 4) << 4)) ^ ((row & 7) << 4);
            bh[ni] = *(const f16x8*)((const char*)Bh + off);
            bl[ni] = *(const f16x8*)((const char*)Bl + off);
          }
#pragma unroll
          for (int mi = 0; mi < 4; ++mi)
#pragma unroll
            for (int ni = 0; ni < 4; ++ni) {
              acc[mi][ni] = __builtin_amdgcn_mfma_f32_16x16x32_f16(ah[mi], bh[ni], acc[mi][ni], 0, 0, 0);
              acc[mi][ni] = __builtin_amdgcn_mfma_f32_16x16x32_f16(ah[mi], bl[ni], acc[mi][ni], 0, 0, 0);
              acc[mi][ni] = __builtin_amdgcn_mfma_f32_16x16x32_f16(al[mi], bh[ni], acc[mi][ni], 0, 0, 0);
            }
        }
      }
      __syncthreads();
    }
    if (t < 256) {
#pragma unroll
      for (int ni = 0; ni < 4; ++ni) {
        int col = n0 + wn * 64 + ni * 16 + (lane & 15);
        float bias = bih[col] + bhh[col];
#pragma unroll
        for (int mi = 0; mi < 4; ++mi) {
          int rbase = m0 + wm * 64 + mi * 16 + ((lane >> 4) << 2);
#pragma unroll
          for (int r = 0; r < 4; ++r)
            __hip_atomic_store(&xh[(size_t)(rbase + r) * DH + col],
                               acc[mi][ni][r] + bias, __ATOMIC_RELAXED,
                               __HIP_MEMORY_SCOPE_AGENT);
        }
      }
    }
    __syncthreads();   // per-thread vmcnt drain + barrier: all sc1 stores done
    if (tid == 0)
      __hip_atomic_fetch_add(&done[m0 / BM], 1, __ATOMIC_RELAXED,
                             __HIP_MEMORY_SCOPE_AGENT);
    return;
  }

  // ---------------- Recurrence role (R9 body + relaxed polling) -------------
  const int b    = bid;
  const int lane = tid & 63;
  const int wv   = tid >> 6;      // 0..7
  const int r    = lane >> 4;     // 0..3
  const int c    = lane & 15;     // 0..15
  const int jb   = wv * 32 + r * 8;

  float (*hs)[DH] = (float (*)[DH])Ah;   // reuse 2KB of the GEMM LDS

  f32x2 w2[8][8];
#pragma unroll
  for (int j = 0; j < 8; ++j)
#pragma unroll
    for (int q = 0; q < 4; ++q) {
      float4 v = *(const float4*)&Whh[(size_t)(jb + j) * DH + 64 * q + 4 * c];
      f32x2 lo; lo[0] = v.x; lo[1] = v.y;
      f32x2 hi; hi[0] = v.z; hi[1] = v.w;
      w2[j][2 * q]     = lo;
      w2[j][2 * q + 1] = hi;
    }

  const bool writer = (c < 8);
  const int  j      = jb + (c & 7);
  float* pcol = xh + (size_t)b * DH + j;
  const char* hb0 = (const char*)&hs[0][0] + 16 * c;
  const char* hb1 = (const char*)&hs[1][0] + 16 * c;

  int tknown = 0;   // uniform across block; monotone scan of done[]
#define WAITXP(S2)                                                             \
  while (tknown <= (S2)) {                                                     \
    if (__hip_atomic_load(&done[tknown], __ATOMIC_RELAXED,                     \
                          __HIP_MEMORY_SCOPE_AGENT) == 2) ++tknown;            \
  }

  if (tid < DH) hs[0][tid] = 0.0f;
  WAITXP(1)
  float xpc = 0.0f, xp1 = 0.0f;
  if (writer) {
    xpc = __hip_atomic_load(pcol, __ATOMIC_RELAXED, __HIP_MEMORY_SCOPE_AGENT);
    xp1 = __hip_atomic_load(pcol + BH, __ATOMIC_RELAXED, __HIP_MEMORY_SCOPE_AGENT);
  }
  __syncthreads();

#define STEP(S, P)                                                             \
  {                                                                            \
    float xp2 = 0.0f;                                                          \
    if ((S) + 2 < T_STEPS) {                                                   \
      WAITXP((S) + 2)                                                          \
      if (writer)                                                              \
        xp2 = __hip_atomic_load(pcol + ((size_t)(S) + 2) * BH,                 \
                                __ATOMIC_RELAXED, __HIP_MEMORY_SCOPE_AGENT);   \
    }                                                                          \
    const char* hb = (P) ? hb1 : hb0;                                          \
    float4 hq0 = *(const float4*)(hb);                                         \
    float4 hq1 = *(const float4*)(hb + 256);                                   \
    float4 hq2 = *(const float4*)(hb + 512);                                   \
    float4 hq3 = *(const float4*)(hb + 768);                                   \
    f32x2 hp[8];                                                               \
    hp[0][0] = hq0.x; hp[0][1] = hq0.y;  hp[1][0] = hq0.z; hp[1][1] = hq0.w;   \
    hp[2][0] = hq1.x; hp[2][1] = hq1.y;  hp[3][0] = hq1.z; hp[3][1] = hq1.w;   \
    hp[4][0] = hq2.x; hp[4][1] = hq2.y;  hp[5][0] = hq2.z; hp[5][1] = hq2.w;   \
    hp[6][0] = hq3.x; hp[6][1] = hq3.y;  hp[7][0] = hq3.z; hp[7][1] = hq3.w;   \
    f32x2 acc[8];                                                              \
    _Pragma("unroll")                                                          \
    for (int jj = 0; jj < 8; ++jj) acc[jj] = w2[jj][0] * hp[0];                \
    _Pragma("unroll")                                                          \
    for (int kp = 1; kp < 8; ++kp)                                             \
      _Pragma("unroll")                                                        \
      for (int jj = 0; jj < 8; ++jj)                                           \
        acc[jj] = __builtin_elementwise_fma(w2[jj][kp], hp[kp], acc[jj]);      \
    float a[8];                                                                \
    _Pragma("unroll")                                                          \
    for (int jj = 0; jj < 8; ++jj) a[jj] = acc[jj][0] + acc[jj][1];            \
    _Pragma("unroll")                                                          \
    for (int jj = 0; jj < 8; ++jj) a[jj] = dpp_ror_sum16(a[jj]);               \
    const int cc = c & 7;                                                      \
    float v0 = (cc & 1) ? a[1] : a[0];                                         \
    float v1 = (cc & 1) ? a[3] : a[2];                                         \
    float v2 = (cc & 1) ? a[5] : a[4];                                         \
    float v3 = (cc & 1) ? a[7] : a[6];                                         \
    float u0 = (cc & 2) ? v1 : v0;                                             \
    float u1 = (cc & 2) ? v3 : v2;                                             \
    float sum = (cc & 4) ? u1 : u0;                                            \
    float h = tanh_fast(sum + xpc);                                            \
    if (writer) {                                                              \
      hs[(P) ^ 1][j] = h;                                                      \
      pcol[(size_t)(S) * BH] = h;                                              \
    }                                                                          \
    xpc = xp1; xp1 = xp2;                                                      \
    LDS_BARRIER();                                                             \
  }

  for (int s = 0; s < T_STEPS; s += 2) {
    STEP(s, 0)
    STEP(s + 1, 1)
  }
#undef STEP
#undef WAITXP
}

extern "C" void kernel_launch(void* const* d_in, const int* in_sizes, int n_in,
                              void* d_out, int out_size, void* d_ws, size_t ws_size,
                              hipStream_t stream) {
  const float* x   = (const float*)d_in[0];
  const float* Wih = (const float*)d_in[1];
  const float* Whh = (const float*)d_in[2];
  const float* bih = (const float*)d_in[3];
  const float* bhh = (const float*)d_in[4];
  float* out = (float*)d_out;
  int*   done = (int*)d_ws;

  hipMemsetAsync(done, 0, T_STEPS * sizeof(int), stream);
  rnn_fused<<<REC_BLOCKS + 2 * T_STEPS, dim3(512), 0, stream>>>(
      x, Wih, Whh, bih, bhh, out, done);
}